// Round 3
// baseline (476.862 us; speedup 1.0000x reference)
//
#include <hip/hip_runtime.h>
#include <hip/hip_bf16.h>
#include <math.h>

#define NNODES 50000
#define NEDGES 600000
#define FDIM   128
#define NCLS   40

typedef __hip_bfloat16  bf16;
typedef __hip_bfloat162 bf162;
typedef short bf16x8 __attribute__((ext_vector_type(8)));
typedef float f32x4  __attribute__((ext_vector_type(4)));

// flags layout (in ws): [0]=alloc counter, [1]=edge is64, [2]=x fp32, [3]=W fp32
// ---------------------------------------------------------------------------
// Edge dtype: int64 data has all-zero odd 32-bit words (high halves of values
// < 2^31). int32 data has random values at odd words.
__global__ void k_detect_e(const unsigned int* ei, int* flagp) {
    __shared__ int cnt;
    if (threadIdx.x == 0) cnt = 0;
    __syncthreads();
    int nz = 0;
    for (int i = threadIdx.x; i < 2048; i += 256)
        if (ei[2 * i + 1] != 0u) nz++;
    atomicAdd(&cnt, nz);
    __syncthreads();
    if (threadIdx.x == 0) *flagp = (cnt == 0) ? 1 : 0;   // 1 => int64
}

// Float dtype: look at the LOW 16 bits of each 32-bit word. If the array is
// bf16, those are bf16 values of sane magnitude -> exponent field in
// [100,140] essentially always. If fp32, they are random mantissa bits ->
// in-range only ~16% of the time.
__global__ void k_detect_f(const unsigned int* p, int* flagp) {
    __shared__ int cnt;
    if (threadIdx.x == 0) cnt = 0;
    __syncthreads();
    int inr = 0;
    for (int i = threadIdx.x; i < 2048; i += 256) {
        unsigned int e = (p[i] >> 7) & 0xFFu;
        if (e >= 100u && e <= 140u) inr++;
    }
    atomicAdd(&cnt, inr);
    __syncthreads();
    if (threadIdx.x == 0) *flagp = (cnt < 1024) ? 1 : 0;  // 1 => fp32
}

__device__ __forceinline__ int edge_val(const int* e32, const long long* e64,
                                        int is64, int idx) {
    return is64 ? (int)e64[idx] : e32[idx];
}
__device__ __forceinline__ float ldf(const void* p, int fp32, int idx) {
    return fp32 ? ((const float*)p)[idx]
                : __bfloat162float(((const bf16*)p)[idx]);
}

// ---------------------------------------------------------------------------
__global__ void k_deg(const int* e32, const long long* e64, const int* flags,
                      int* deg) {
    int i = blockIdx.x * 256 + threadIdx.x;
    if (i >= NEDGES) return;
    int dst = edge_val(e32, e64, flags[1], NEDGES + i);
    atomicAdd(&deg[dst], 1);
}

__global__ void k_alloc(const int* deg, int* counter, int* start, int* cursor) {
    __shared__ int s[256];
    __shared__ int sbase;
    int t = threadIdx.x;
    int i = blockIdx.x * 256 + t;
    int d = (i < NNODES) ? deg[i] : 0;
    s[t] = d;
    __syncthreads();
    for (int off = 1; off < 256; off <<= 1) {
        int v = (t >= off) ? s[t - off] : 0;
        __syncthreads();
        s[t] += v;
        __syncthreads();
    }
    if (t == 255) sbase = atomicAdd(counter, s[255]);
    __syncthreads();
    if (i < NNODES) {
        int st = sbase + s[t] - d;
        start[i] = st;
        cursor[i] = st;
    }
}

__global__ void k_fill(const int* e32, const long long* e64, const int* flags,
                       int* cursor, int* edge_src) {
    int i = blockIdx.x * 256 + threadIdx.x;
    if (i >= NEDGES) return;
    int is64 = flags[1];
    int src = edge_val(e32, e64, is64, i);
    int dst = edge_val(e32, e64, is64, NEDGES + i);
    int p = atomicAdd(&cursor[dst], 1);
    edge_src[p] = src;
}

// ---------------------------------------------------------------------------
// x -> bf16, dtype-aware (2 elements per thread)
__global__ void k_cvt_x(const void* xin, const int* flags, bf162* xout) {
    int i = blockIdx.x * 256 + threadIdx.x;
    if (i >= NNODES * FDIM / 2) return;
    if (flags[2]) {
        float2 v = ((const float2*)xin)[i];
        bf162 o;
        o.x = __float2bfloat16(v.x);
        o.y = __float2bfloat16(v.y);
        xout[i] = o;
    } else {
        xout[i] = ((const bf162*)xin)[i];
    }
}

// biases -> fp32, layout [bl1|bl2|bl3|blin1|blin2(40, padded)]
__global__ void k_cvt_bias(const void* b1, const void* b2, const void* b3,
                           const void* b4, const void* b5, const int* flags,
                           float* out) {
    int t = blockIdx.x * 256 + threadIdx.x;
    if (t >= 5 * 128) return;
    int which = t >> 7, idx = t & 127;
    const void* srcs[5] = {b1, b2, b3, b4, b5};
    int n = (which == 4) ? NCLS : 128;
    float v = 0.f;
    if (idx < n) v = ldf(srcs[which], flags[3], idx);
    out[t] = v;
}

// ---------------------------------------------------------------------------
// Mean aggregation: one wave per destination node; each neighbor row read is
// 64 lanes x 4B = one coalesced 256B row. fp32 accumulation.
__global__ void k_agg(const bf16* __restrict__ x, const int* __restrict__ start,
                      const int* __restrict__ deg, const int* __restrict__ edge_src,
                      bf16* __restrict__ aggb) {
    int w = threadIdx.x >> 6, lane = threadIdx.x & 63;
    int d = blockIdx.x * 4 + w;
    if (d >= NNODES) return;
    int s = start[d], dg = deg[d];
    const bf162* xp = (const bf162*)x;
    float a0 = 0.f, a1 = 0.f;
    for (int i = 0; i < dg; i++) {
        int src = edge_src[s + i];
        bf162 v = xp[src * 64 + lane];
        a0 += __bfloat162float(v.x);
        a1 += __bfloat162float(v.y);
    }
    float inv = (dg > 0) ? 1.f / (float)dg : 0.f;
    bf162 o;
    o.x = __float2bfloat16(a0 * inv);
    o.y = __float2bfloat16(a1 * inv);
    ((bf162*)aggb)[d * 64 + lane] = o;
}

// ---------------------------------------------------------------------------
// Weight pre-pack into MFMA B-fragment layout (dtype-aware):
// frag(kt, nt), lane: elem j = W[kbase + (lane>>4)*8 + j][nt*16 + (lane&15)]
// Frags: layer1 0..63 | layer2 64..127 | layer3 128..191 | lin1 192..223 |
//        lin2 224..235 (KT=4, NT=3, cols >=40 zero-padded)
__global__ void k_pack(const void* Wl1, const void* Wr1, const void* Wl2,
                       const void* Wr2, const void* Wl3, const void* Wr3,
                       const void* Wlin1, const void* Wlin2, const int* flags,
                       bf16x8* packed) {
    int tid = blockIdx.x * 256 + threadIdx.x;
    int frag = tid >> 6, lane = tid & 63;
    if (frag >= 236) return;
    int fp32 = flags[3];
    int q = lane >> 4, l16 = lane & 15;
    const void* W;
    int kbase, n, ldw = 128, nvalid = 128;
    if (frag < 192) {
        int g = frag >> 6, local = frag & 63;
        int kt = local >> 3, nt = local & 7;
        const void* Wl = (g == 0) ? Wl1 : (g == 1) ? Wl2 : Wl3;
        const void* Wr = (g == 0) ? Wr1 : (g == 1) ? Wr2 : Wr3;
        W = (kt < 4) ? Wl : Wr;
        kbase = (kt & 3) * 32;
        n = nt * 16 + l16;
    } else if (frag < 224) {
        int local = frag - 192;
        int kt = local >> 3, nt = local & 7;
        W = Wlin1;
        kbase = kt * 32;
        n = nt * 16 + l16;
    } else {
        int local = frag - 224;
        int kt = local / 3, nt = local % 3;
        W = Wlin2;
        kbase = kt * 32;
        n = nt * 16 + l16;
        ldw = NCLS;
        nvalid = NCLS;
    }
    bf16x8 v;
#pragma unroll
    for (int j = 0; j < 8; j++) {
        float e = 0.f;
        if (n < nvalid) e = ldf(W, fp32, (kbase + q * 8 + j) * ldw + n);
        bf16 h = __float2bfloat16(e);
        v[j] = *(const short*)&h;
    }
    packed[frag * 64 + lane] = v;
}

// ---------------------------------------------------------------------------
// MFMA GEMM, no LDS. Block = 64 rows x (NT_TOTAL*16) cols, 4 waves.
// A-frags 16B-contiguous global loads; B-frags from pre-packed buffer.
// HAS_AGG: K = 256 with kt<KT/2 reading xa (agg) and kt>=KT/2 reading xb.
template <int KT_TOTAL, bool HAS_AGG, int NT_TOTAL, int NT_PER_WAVE, bool RELU,
          bool F32OUT, int OUTW>
__global__ void k_gemm(const bf16* __restrict__ xa, const bf16* __restrict__ xb,
                       const bf16x8* __restrict__ packed,
                       const float* __restrict__ bias, void* __restrict__ outp) {
    const int lane = threadIdx.x & 63;
    const int wave = threadIdx.x >> 6;
    const int q = lane >> 4, l16 = lane & 15;
    const int ntbase = wave * NT_PER_WAVE;
    if (ntbase >= NT_TOTAL) return;
    const int rowbase = blockIdx.x * 64;

    f32x4 acc[4][NT_PER_WAVE];
#pragma unroll
    for (int mt = 0; mt < 4; mt++)
#pragma unroll
        for (int n = 0; n < NT_PER_WAVE; n++)
            acc[mt][n] = (f32x4){0.f, 0.f, 0.f, 0.f};

    int rowc[4];
#pragma unroll
    for (int mt = 0; mt < 4; mt++) {
        int row = rowbase + mt * 16 + l16;
        rowc[mt] = (row < NNODES) ? row : (NNODES - 1);
    }

#pragma unroll
    for (int kt = 0; kt < KT_TOTAL; kt++) {
        const bf16* src;
        int klocal;
        if constexpr (HAS_AGG) {
            if (kt < KT_TOTAL / 2) { src = xa; klocal = kt * 32; }
            else                   { src = xb; klocal = (kt - KT_TOTAL / 2) * 32; }
        } else {
            src = xb; klocal = kt * 32;
        }
        bf16x8 a[4];
#pragma unroll
        for (int mt = 0; mt < 4; mt++)
            a[mt] = *(const bf16x8*)(src + rowc[mt] * FDIM + klocal + q * 8);
        bf16x8 b[NT_PER_WAVE];
#pragma unroll
        for (int n = 0; n < NT_PER_WAVE; n++)
            b[n] = packed[(kt * NT_TOTAL + ntbase + n) * 64 + lane];
#pragma unroll
        for (int mt = 0; mt < 4; mt++)
#pragma unroll
            for (int n = 0; n < NT_PER_WAVE; n++)
                acc[mt][n] = __builtin_amdgcn_mfma_f32_16x16x32_bf16(
                    a[mt], b[n], acc[mt][n], 0, 0, 0);
    }

#pragma unroll
    for (int n = 0; n < NT_PER_WAVE; n++) {
        int col = (ntbase + n) * 16 + l16;
        float bv = (col < OUTW) ? bias[col] : 0.f;
#pragma unroll
        for (int mt = 0; mt < 4; mt++) {
#pragma unroll
            for (int r = 0; r < 4; r++) {
                int row = rowbase + mt * 16 + q * 4 + r;
                if (row < NNODES && col < OUTW) {
                    float v = acc[mt][n][r] + bv;
                    if (RELU) v = fmaxf(v, 0.f);
                    if (F32OUT) ((float*)outp)[row * OUTW + col] = v;
                    else ((bf16*)outp)[row * OUTW + col] = __float2bfloat16(v);
                }
            }
        }
    }
}

// ---------------------------------------------------------------------------
// Output is fp32 (reference output dtype is float32 — round-2 evidence:
// bf16 writes left the upper half of d_out zero => absmax exactly max|ref|).
__global__ void k_softmax(const float* __restrict__ logits, float* __restrict__ out) {
    int w = threadIdx.x >> 6, lane = threadIdx.x & 63;
    int nidx = blockIdx.x * 4 + w;
    if (nidx >= NNODES) return;
    float v = (lane < NCLS) ? logits[nidx * NCLS + lane] : -INFINITY;
    float m = v;
#pragma unroll
    for (int off = 32; off; off >>= 1) m = fmaxf(m, __shfl_xor(m, off));
    float e = (lane < NCLS) ? expf(v - m) : 0.f;
    float s = e;
#pragma unroll
    for (int off = 32; off; off >>= 1) s += __shfl_xor(s, off);
    float l = m + logf(s);
    if (lane < NCLS) out[nidx * NCLS + lane] = v - l;
}

// ---------------------------------------------------------------------------
extern "C" void kernel_launch(void* const* d_in, const int* in_sizes, int n_in,
                              void* d_out, int out_size, void* d_ws, size_t ws_size,
                              hipStream_t stream) {
    const void* x = d_in[0];
    const int* e32 = (const int*)d_in[1];
    const long long* e64 = (const long long*)d_in[1];

    char* ws = (char*)d_ws;
    size_t off = 0;
    auto take = [&](size_t bytes) {
        void* p = ws + off;
        off = (off + bytes + 255) & ~(size_t)255;
        return p;
    };
    int* deg      = (int*)take(NNODES * 4);
    int* start    = (int*)take(NNODES * 4);
    int* cursor   = (int*)take(NNODES * 4);
    int* flags    = (int*)take(256);           // [0]=counter [1]=is64 [2]=xfp32 [3]=wfp32
    int* edge_src = (int*)take(NEDGES * 4);
    bf16x8* packed = (bf16x8*)take(236 * 64 * 16);
    float* biasf  = (float*)take(5 * 128 * 4);
    bf16* xb      = (bf16*)take((size_t)NNODES * FDIM * 2);   // aliases bufB
    bf16* aggb    = (bf16*)take((size_t)NNODES * FDIM * 2);   // aliases logits
    bf16* bufA    = (bf16*)take((size_t)NNODES * FDIM * 2);
    float* logits = (float*)take((size_t)NNODES * NCLS * 4);
    bf16* bufB    = xb;        // x dead after layer-1 gemm

    hipMemsetAsync(deg, 0, NNODES * 4, stream);
    hipMemsetAsync(flags, 0, 256, stream);

    k_detect_e<<<1, 256, 0, stream>>>((const unsigned int*)d_in[1], flags + 1);
    k_detect_f<<<1, 256, 0, stream>>>((const unsigned int*)d_in[0], flags + 2);
    k_detect_f<<<1, 256, 0, stream>>>((const unsigned int*)d_in[2], flags + 3);

    const int EB = (NEDGES + 255) / 256;
    const int NB = (NNODES + 255) / 256;
    k_deg<<<EB, 256, 0, stream>>>(e32, e64, flags, deg);
    k_alloc<<<NB, 256, 0, stream>>>(deg, flags, start, cursor);
    k_fill<<<EB, 256, 0, stream>>>(e32, e64, flags, cursor, edge_src);

    k_cvt_x<<<(NNODES * FDIM / 2 + 255) / 256, 256, 0, stream>>>(x, flags, (bf162*)xb);
    k_cvt_bias<<<3, 256, 0, stream>>>(d_in[3], d_in[6], d_in[9], d_in[12],
                                      d_in[14], flags, biasf);
    k_pack<<<59, 256, 0, stream>>>(d_in[2], d_in[4], d_in[5], d_in[7], d_in[8],
                                   d_in[10], d_in[11], d_in[13], flags, packed);

    const int AB = (NNODES + 3) / 4;
    const int GB = (NNODES + 63) / 64;

    // layer 1: xb -> bufA
    k_agg<<<AB, 256, 0, stream>>>(xb, start, deg, edge_src, aggb);
    k_gemm<8, true, 8, 2, true, false, 128><<<GB, 256, 0, stream>>>(
        aggb, xb, packed + 0 * 64, biasf + 0, bufA);
    // layer 2: bufA -> bufB (aliases xb; xb dead now)
    k_agg<<<AB, 256, 0, stream>>>(bufA, start, deg, edge_src, aggb);
    k_gemm<8, true, 8, 2, true, false, 128><<<GB, 256, 0, stream>>>(
        aggb, bufA, packed + 64 * 64, biasf + 128, bufB);
    // layer 3: bufB -> bufA
    k_agg<<<AB, 256, 0, stream>>>(bufB, start, deg, edge_src, aggb);
    k_gemm<8, true, 8, 2, true, false, 128><<<GB, 256, 0, stream>>>(
        aggb, bufB, packed + 128 * 64, biasf + 256, bufA);
    // lin1: bufA -> bufB
    k_gemm<4, false, 8, 2, true, false, 128><<<GB, 256, 0, stream>>>(
        nullptr, bufA, packed + 192 * 64, biasf + 384, bufB);
    // lin2: bufB -> logits (fp32)
    k_gemm<4, false, 3, 1, false, true, 40><<<GB, 256, 0, stream>>>(
        nullptr, bufB, packed + 224 * 64, biasf + 512, logits);
    // log_softmax -> out (fp32)
    k_softmax<<<AB, 256, 0, stream>>>(logits, (float*)d_out);
}

// Round 4
// 351.014 us; speedup vs baseline: 1.3585x; 1.3585x over previous
//
#include <hip/hip_runtime.h>
#include <hip/hip_bf16.h>
#include <math.h>

#define NNODES 50000
#define NEDGES 600000
#define FDIM   128
#define NCLS   40

typedef __hip_bfloat16  bf16;
typedef __hip_bfloat162 bf162;
typedef short bf16x8 __attribute__((ext_vector_type(8)));
typedef short bf16x4 __attribute__((ext_vector_type(4)));
typedef float f32x4  __attribute__((ext_vector_type(4)));

__device__ __forceinline__ float b2f(short u) {
    unsigned int t = ((unsigned int)(unsigned short)u) << 16;
    union { unsigned int i; float f; } cv;
    cv.i = t;
    return cv.f;
}

// flags layout (in ws): [0]=alloc counter, [1]=edge is64, [2]=x fp32, [3]=W fp32
// ---------------------------------------------------------------------------
// Merged dtype detection (3 blocks):
//  block 0: edge int64? (odd 32-bit words all zero)
//  block 1: x fp32?  block 2: W fp32?  (low-16 exponent-field statistics)
__global__ void k_detect(const unsigned int* ei, const unsigned int* xp,
                         const unsigned int* wp, int* flags) {
    __shared__ int cnt;
    if (threadIdx.x == 0) cnt = 0;
    __syncthreads();
    int b = blockIdx.x;
    if (b == 0) {
        int nz = 0;
        for (int i = threadIdx.x; i < 2048; i += 256)
            if (ei[2 * i + 1] != 0u) nz++;
        atomicAdd(&cnt, nz);
        __syncthreads();
        if (threadIdx.x == 0) flags[1] = (cnt == 0) ? 1 : 0;
    } else {
        const unsigned int* p = (b == 1) ? xp : wp;
        int inr = 0;
        for (int i = threadIdx.x; i < 2048; i += 256) {
            unsigned int e = (p[i] >> 7) & 0xFFu;
            if (e >= 100u && e <= 140u) inr++;
        }
        atomicAdd(&cnt, inr);
        __syncthreads();
        if (threadIdx.x == 0) flags[b + 1] = (cnt < 1024) ? 1 : 0;
    }
}

__device__ __forceinline__ int edge_val(const int* e32, const long long* e64,
                                        int is64, int idx) {
    return is64 ? (int)e64[idx] : e32[idx];
}
__device__ __forceinline__ float ldf(const void* p, int fp32, int idx) {
    return fp32 ? ((const float*)p)[idx]
                : __bfloat162float(((const bf16*)p)[idx]);
}

// ---------------------------------------------------------------------------
__global__ void k_deg(const int* e32, const long long* e64, const int* flags,
                      int* deg) {
    int i = blockIdx.x * 256 + threadIdx.x;
    if (i >= NEDGES) return;
    int dst = edge_val(e32, e64, flags[1], NEDGES + i);
    atomicAdd(&deg[dst], 1);
}

__global__ void k_alloc(const int* deg, int* counter, int* start, int* cursor) {
    __shared__ int s[256];
    __shared__ int sbase;
    int t = threadIdx.x;
    int i = blockIdx.x * 256 + t;
    int d = (i < NNODES) ? deg[i] : 0;
    s[t] = d;
    __syncthreads();
    for (int off = 1; off < 256; off <<= 1) {
        int v = (t >= off) ? s[t - off] : 0;
        __syncthreads();
        s[t] += v;
        __syncthreads();
    }
    if (t == 255) sbase = atomicAdd(counter, s[255]);
    __syncthreads();
    if (i < NNODES) {
        int st = sbase + s[t] - d;
        start[i] = st;
        cursor[i] = st;
    }
}

__global__ void k_fill(const int* e32, const long long* e64, const int* flags,
                       int* cursor, int* edge_src) {
    int i = blockIdx.x * 256 + threadIdx.x;
    if (i >= NEDGES) return;
    int is64 = flags[1];
    int src = edge_val(e32, e64, is64, i);
    int dst = edge_val(e32, e64, is64, NEDGES + i);
    int p = atomicAdd(&cursor[dst], 1);
    edge_src[p] = src;
}

// ---------------------------------------------------------------------------
// x -> bf16, dtype-aware, 4 elements per thread (16B fp32 read / 8B write)
__global__ void k_cvt_x(const void* xin, const int* flags, void* xout) {
    int i = blockIdx.x * 256 + threadIdx.x;
    if (i >= NNODES * FDIM / 4) return;
    if (flags[2]) {
        float4 v = ((const float4*)xin)[i];
        bf16x4 o;
        bf16 h0 = __float2bfloat16(v.x); o[0] = *(const short*)&h0;
        bf16 h1 = __float2bfloat16(v.y); o[1] = *(const short*)&h1;
        bf16 h2 = __float2bfloat16(v.z); o[2] = *(const short*)&h2;
        bf16 h3 = __float2bfloat16(v.w); o[3] = *(const short*)&h3;
        ((bf16x4*)xout)[i] = o;
    } else {
        ((uint2*)xout)[i] = ((const uint2*)xin)[i];
    }
}

// ---------------------------------------------------------------------------
// Weight pre-pack into MFMA B-fragment layout (dtype-aware), plus bias
// conversion folded in (blocks 59..61).
// frag(kt, nt), lane: elem j = W[kbase + (lane>>4)*8 + j][nt*16 + (lane&15)]
// Frags: layer1 0..63 | layer2 64..127 | layer3 128..191 | lin1 192..223 |
//        lin2 224..235 (KT=4, NT=3, cols >=40 zero-padded)
__global__ void k_pack(const void* Wl1, const void* Wr1, const void* Wl2,
                       const void* Wr2, const void* Wl3, const void* Wr3,
                       const void* Wlin1, const void* Wlin2,
                       const void* b1, const void* b2, const void* b3,
                       const void* b4, const void* b5,
                       const int* flags, bf16x8* packed, float* biasf) {
    int fp32 = flags[3];
    if (blockIdx.x >= 59) {
        int t = (blockIdx.x - 59) * 256 + threadIdx.x;
        if (t >= 5 * 128) return;
        int which = t >> 7, idx = t & 127;
        const void* srcs[5] = {b1, b2, b3, b4, b5};
        int n = (which == 4) ? NCLS : 128;
        float v = 0.f;
        if (idx < n) v = ldf(srcs[which], fp32, idx);
        biasf[t] = v;
        return;
    }
    int tid = blockIdx.x * 256 + threadIdx.x;
    int frag = tid >> 6, lane = tid & 63;
    int q = lane >> 4, l16 = lane & 15;
    const void* W;
    int kbase, n, ldw = 128, nvalid = 128;
    if (frag < 192) {
        int g = frag >> 6, local = frag & 63;
        int kt = local >> 3, nt = local & 7;
        const void* Wl = (g == 0) ? Wl1 : (g == 1) ? Wl2 : Wl3;
        const void* Wr = (g == 0) ? Wr1 : (g == 1) ? Wr2 : Wr3;
        W = (kt < 4) ? Wl : Wr;
        kbase = (kt & 3) * 32;
        n = nt * 16 + l16;
    } else if (frag < 224) {
        int local = frag - 192;
        int kt = local >> 3, nt = local & 7;
        W = Wlin1;
        kbase = kt * 32;
        n = nt * 16 + l16;
    } else {
        int local = frag - 224;
        int kt = local / 3, nt = local % 3;
        W = Wlin2;
        kbase = kt * 32;
        n = nt * 16 + l16;
        ldw = NCLS;
        nvalid = NCLS;
    }
    bf16x8 v;
#pragma unroll
    for (int j = 0; j < 8; j++) {
        float e = 0.f;
        if (n < nvalid) e = ldf(W, fp32, (kbase + q * 8 + j) * ldw + n);
        bf16 h = __float2bfloat16(e);
        v[j] = *(const short*)&h;
    }
    packed[frag * 64 + lane] = v;
}

// ---------------------------------------------------------------------------
// Mean aggregation v2 — latency-optimized gather.
// One wave per dst node. Lane layout: group g = lane>>4 (4 groups), col
// sub c = lane&15 (16B = 8 cols each). All <=64 edge indices preloaded in
// one coalesced load (one per lane), distributed via shfl. Main loop
// processes 8 neighbors/iteration with 2 independent 16B gathers in flight.
// Cross-group reduce via shfl_xor(16/32); group 0 writes the 256B row.
__global__ void k_agg(const bf16* __restrict__ x, const int* __restrict__ start,
                      const int* __restrict__ deg, const int* __restrict__ edge_src,
                      bf16* __restrict__ aggb) {
    int w = threadIdx.x >> 6, lane = threadIdx.x & 63;
    int d = blockIdx.x * 4 + w;
    if (d >= NNODES) return;
    int s = start[d], dg = deg[d];
    int g = lane >> 4, c = lane & 15;
    int dcap = dg < 64 ? dg : 64;
    int eidx = (lane < dcap) ? edge_src[s + lane] : 0;
    float acc[8];
#pragma unroll
    for (int e = 0; e < 8; e++) acc[e] = 0.f;
    int i = 0;
    for (; i + 8 <= dcap; i += 8) {
        int i0 = __shfl(eidx, i + g);
        int i1 = __shfl(eidx, i + 4 + g);
        bf16x8 v0 = *(const bf16x8*)(x + (size_t)i0 * FDIM + c * 8);
        bf16x8 v1 = *(const bf16x8*)(x + (size_t)i1 * FDIM + c * 8);
#pragma unroll
        for (int e = 0; e < 8; e++) acc[e] += b2f(v0[e]) + b2f(v1[e]);
    }
    for (; i < dcap; i += 4) {
        int j = i + g;
        int jj = (j < dcap) ? j : (dcap - 1);
        int i0 = __shfl(eidx, jj);
        bf16x8 v0 = *(const bf16x8*)(x + (size_t)i0 * FDIM + c * 8);
        if (j < dcap) {
#pragma unroll
            for (int e = 0; e < 8; e++) acc[e] += b2f(v0[e]);
        }
    }
    if (dg > 64) {                       // essentially never for Poisson(12)
        for (int t = 64; t < dg; t++) {
            int src = edge_src[s + t];
            bf16x8 v0 = *(const bf16x8*)(x + (size_t)src * FDIM + c * 8);
            if (g == 0) {
#pragma unroll
                for (int e = 0; e < 8; e++) acc[e] += b2f(v0[e]);
            }
        }
    }
#pragma unroll
    for (int e = 0; e < 8; e++) {
        float a = acc[e];
        a += __shfl_xor(a, 16);
        a += __shfl_xor(a, 32);
        acc[e] = a;
    }
    if (g == 0) {
        float inv = (dg > 0) ? 1.f / (float)dg : 0.f;
        bf16x8 o;
#pragma unroll
        for (int e = 0; e < 8; e++) {
            bf16 h = __float2bfloat16(acc[e] * inv);
            o[e] = *(const short*)&h;
        }
        *(bf16x8*)(aggb + (size_t)d * FDIM + c * 8) = o;
    }
}

// ---------------------------------------------------------------------------
// MFMA GEMM, no LDS. Block = 64 rows x (NT_TOTAL*16) cols, 4 waves.
// A-frags 16B-contiguous global loads; B-frags from pre-packed buffer.
// HAS_AGG: K = 256 with kt<KT/2 reading xa (agg) and kt>=KT/2 reading xb.
template <int KT_TOTAL, bool HAS_AGG, int NT_TOTAL, int NT_PER_WAVE, bool RELU,
          bool F32OUT, int OUTW>
__global__ void k_gemm(const bf16* __restrict__ xa, const bf16* __restrict__ xb,
                       const bf16x8* __restrict__ packed,
                       const float* __restrict__ bias, void* __restrict__ outp) {
    const int lane = threadIdx.x & 63;
    const int wave = threadIdx.x >> 6;
    const int q = lane >> 4, l16 = lane & 15;
    const int ntbase = wave * NT_PER_WAVE;
    if (ntbase >= NT_TOTAL) return;
    const int rowbase = blockIdx.x * 64;

    f32x4 acc[4][NT_PER_WAVE];
#pragma unroll
    for (int mt = 0; mt < 4; mt++)
#pragma unroll
        for (int n = 0; n < NT_PER_WAVE; n++)
            acc[mt][n] = (f32x4){0.f, 0.f, 0.f, 0.f};

    int rowc[4];
#pragma unroll
    for (int mt = 0; mt < 4; mt++) {
        int row = rowbase + mt * 16 + l16;
        rowc[mt] = (row < NNODES) ? row : (NNODES - 1);
    }

#pragma unroll
    for (int kt = 0; kt < KT_TOTAL; kt++) {
        const bf16* src;
        int klocal;
        if constexpr (HAS_AGG) {
            if (kt < KT_TOTAL / 2) { src = xa; klocal = kt * 32; }
            else                   { src = xb; klocal = (kt - KT_TOTAL / 2) * 32; }
        } else {
            src = xb; klocal = kt * 32;
        }
        bf16x8 a[4];
#pragma unroll
        for (int mt = 0; mt < 4; mt++)
            a[mt] = *(const bf16x8*)(src + rowc[mt] * FDIM + klocal + q * 8);
        bf16x8 b[NT_PER_WAVE];
#pragma unroll
        for (int n = 0; n < NT_PER_WAVE; n++)
            b[n] = packed[(kt * NT_TOTAL + ntbase + n) * 64 + lane];
#pragma unroll
        for (int mt = 0; mt < 4; mt++)
#pragma unroll
            for (int n = 0; n < NT_PER_WAVE; n++)
                acc[mt][n] = __builtin_amdgcn_mfma_f32_16x16x32_bf16(
                    a[mt], b[n], acc[mt][n], 0, 0, 0);
    }

#pragma unroll
    for (int n = 0; n < NT_PER_WAVE; n++) {
        int col = (ntbase + n) * 16 + l16;
        float bv = (col < OUTW) ? bias[col] : 0.f;
#pragma unroll
        for (int mt = 0; mt < 4; mt++) {
#pragma unroll
            for (int r = 0; r < 4; r++) {
                int row = rowbase + mt * 16 + q * 4 + r;
                if (row < NNODES && col < OUTW) {
                    float v = acc[mt][n][r] + bv;
                    if (RELU) v = fmaxf(v, 0.f);
                    if (F32OUT) ((float*)outp)[row * OUTW + col] = v;
                    else ((bf16*)outp)[row * OUTW + col] = __float2bfloat16(v);
                }
            }
        }
    }
}

// ---------------------------------------------------------------------------
__global__ void k_softmax(const float* __restrict__ logits, float* __restrict__ out) {
    int w = threadIdx.x >> 6, lane = threadIdx.x & 63;
    int nidx = blockIdx.x * 4 + w;
    if (nidx >= NNODES) return;
    float v = (lane < NCLS) ? logits[nidx * NCLS + lane] : -INFINITY;
    float m = v;
#pragma unroll
    for (int off = 32; off; off >>= 1) m = fmaxf(m, __shfl_xor(m, off));
    float e = (lane < NCLS) ? expf(v - m) : 0.f;
    float s = e;
#pragma unroll
    for (int off = 32; off; off >>= 1) s += __shfl_xor(s, off);
    float l = m + logf(s);
    if (lane < NCLS) out[nidx * NCLS + lane] = v - l;
}

// ---------------------------------------------------------------------------
extern "C" void kernel_launch(void* const* d_in, const int* in_sizes, int n_in,
                              void* d_out, int out_size, void* d_ws, size_t ws_size,
                              hipStream_t stream) {
    const void* x = d_in[0];
    const int* e32 = (const int*)d_in[1];
    const long long* e64 = (const long long*)d_in[1];

    char* ws = (char*)d_ws;
    size_t off = 0;
    auto take = [&](size_t bytes) {
        void* p = ws + off;
        off = (off + bytes + 255) & ~(size_t)255;
        return p;
    };
    int* deg      = (int*)take(NNODES * 4);
    int* start    = (int*)take(NNODES * 4);
    int* cursor   = (int*)take(NNODES * 4);
    int* flags    = (int*)take(256);           // [0]=counter [1]=is64 [2]=xfp32 [3]=wfp32
    int* edge_src = (int*)take(NEDGES * 4);
    bf16x8* packed = (bf16x8*)take(236 * 64 * 16);
    float* biasf  = (float*)take(5 * 128 * 4);
    bf16* xb      = (bf16*)take((size_t)NNODES * FDIM * 2);
    bf16* aggb    = (bf16*)take((size_t)NNODES * FDIM * 2);
    bf16* bufA    = (bf16*)take((size_t)NNODES * FDIM * 2);
    float* logits = (float*)take((size_t)NNODES * NCLS * 4);
    bf16* bufB    = xb;        // x dead after layer-1 gemm

    hipMemsetAsync(deg, 0, NNODES * 4, stream);
    hipMemsetAsync(flags, 0, 256, stream);

    k_detect<<<3, 256, 0, stream>>>((const unsigned int*)d_in[1],
                                    (const unsigned int*)d_in[0],
                                    (const unsigned int*)d_in[2], flags);

    const int EB = (NEDGES + 255) / 256;
    const int NB = (NNODES + 255) / 256;
    k_deg<<<EB, 256, 0, stream>>>(e32, e64, flags, deg);
    k_alloc<<<NB, 256, 0, stream>>>(deg, flags, start, cursor);
    k_fill<<<EB, 256, 0, stream>>>(e32, e64, flags, cursor, edge_src);

    k_cvt_x<<<(NNODES * FDIM / 4 + 255) / 256, 256, 0, stream>>>(x, flags, xb);
    k_pack<<<62, 256, 0, stream>>>(d_in[2], d_in[4], d_in[5], d_in[7], d_in[8],
                                   d_in[10], d_in[11], d_in[13],
                                   d_in[3], d_in[6], d_in[9], d_in[12], d_in[14],
                                   flags, packed, biasf);

    const int AB = (NNODES + 3) / 4;
    const int GB = (NNODES + 63) / 64;

    // layer 1: xb -> bufA
    k_agg<<<AB, 256, 0, stream>>>(xb, start, deg, edge_src, aggb);
    k_gemm<8, true, 8, 2, true, false, 128><<<GB, 256, 0, stream>>>(
        aggb, xb, packed + 0 * 64, biasf + 0, bufA);
    // layer 2: bufA -> bufB (aliases xb; xb dead now)
    k_agg<<<AB, 256, 0, stream>>>(bufA, start, deg, edge_src, aggb);
    k_gemm<8, true, 8, 2, true, false, 128><<<GB, 256, 0, stream>>>(
        aggb, bufA, packed + 64 * 64, biasf + 128, bufB);
    // layer 3: bufB -> bufA
    k_agg<<<AB, 256, 0, stream>>>(bufB, start, deg, edge_src, aggb);
    k_gemm<8, true, 8, 2, true, false, 128><<<GB, 256, 0, stream>>>(
        aggb, bufB, packed + 128 * 64, biasf + 256, bufA);
    // lin1: bufA -> bufB
    k_gemm<4, false, 8, 2, true, false, 128><<<GB, 256, 0, stream>>>(
        nullptr, bufA, packed + 192 * 64, biasf + 384, bufB);
    // lin2: bufB -> logits (fp32)
    k_gemm<4, false, 3, 1, false, true, 40><<<GB, 256, 0, stream>>>(
        nullptr, bufB, packed + 224 * 64, biasf + 512, logits);
    // log_softmax -> out (fp32)
    k_softmax<<<AB, 256, 0, stream>>>(logits, (float*)d_out);
}

// Round 5
// 326.730 us; speedup vs baseline: 1.4595x; 1.0743x over previous
//
#include <hip/hip_runtime.h>
#include <hip/hip_bf16.h>
#include <math.h>

#define NNODES 50000
#define NEDGES 600000
#define FDIM   128
#define NCLS   40

typedef __hip_bfloat16  bf16;
typedef __hip_bfloat162 bf162;
typedef short bf16x8 __attribute__((ext_vector_type(8)));
typedef short bf16x4 __attribute__((ext_vector_type(4)));
typedef float f32x4  __attribute__((ext_vector_type(4)));

__device__ __forceinline__ float b2f(short u) {
    unsigned int t = ((unsigned int)(unsigned short)u) << 16;
    union { unsigned int i; float f; } cv;
    cv.i = t;
    return cv.f;
}
__device__ __forceinline__ short f2b(float f) {
    bf16 h = __float2bfloat16(f);
    return *(const short*)&h;
}

// flags: [0]=alloc counter, [1]=edge is64, [2]=x fp32, [3]=W fp32
__device__ __forceinline__ int edge_val(const int* e32, const long long* e64,
                                        int is64, int idx) {
    return is64 ? (int)e64[idx] : e32[idx];
}
__device__ __forceinline__ float ldf(const void* p, int fp32, int idx) {
    return fp32 ? ((const float*)p)[idx]
                : __bfloat162float(((const bf16*)p)[idx]);
}

// ---------------------------------------------------------------------------
// k_init: blocks 0..2 dtype detection, block 3 zero counter, blocks 4.. zero deg
__global__ void k_init(const unsigned int* ei, const unsigned int* xp,
                       const unsigned int* wp, int* flags, int* deg) {
    int b = blockIdx.x;
    if (b < 3) {
        __shared__ int cnt;
        if (threadIdx.x == 0) cnt = 0;
        __syncthreads();
        if (b == 0) {
            int nz = 0;
            for (int i = threadIdx.x; i < 2048; i += 256)
                if (ei[2 * i + 1] != 0u) nz++;
            atomicAdd(&cnt, nz);
            __syncthreads();
            if (threadIdx.x == 0) flags[1] = (cnt == 0) ? 1 : 0;
        } else {
            const unsigned int* p = (b == 1) ? xp : wp;
            int inr = 0;
            for (int i = threadIdx.x; i < 2048; i += 256) {
                unsigned int e = (p[i] >> 7) & 0xFFu;
                if (e >= 100u && e <= 140u) inr++;
            }
            atomicAdd(&cnt, inr);
            __syncthreads();
            if (threadIdx.x == 0) flags[b + 1] = (cnt < 1024) ? 1 : 0;
        }
    } else if (b == 3) {
        if (threadIdx.x == 0) flags[0] = 0;
    } else {
        int i = (b - 4) * 256 + threadIdx.x;
        if (i < NNODES) deg[i] = 0;
    }
}

// ---------------------------------------------------------------------------
// k_stage1: block-range dispatch for deg | cvt_x | pack(+bias)
// blocks [0, 2344): degree count; [2344, 8594): x->bf16; [8594, 8656): pack
#define DEG_BLOCKS 2344
#define CVT_BLOCKS 6250
__global__ void k_stage1(const int* e32, const long long* e64,
                         const void* xin,
                         const void* Wl1, const void* Wr1, const void* Wl2,
                         const void* Wr2, const void* Wl3, const void* Wr3,
                         const void* Wlin1, const void* Wlin2,
                         const void* b1, const void* b2, const void* b3,
                         const void* b4, const void* b5,
                         const int* flags, int* deg, void* xout,
                         bf16x8* packed, float* biasf) {
    int b = blockIdx.x;
    if (b < DEG_BLOCKS) {
        int i = b * 256 + threadIdx.x;
        if (i >= NEDGES) return;
        int dst = edge_val(e32, e64, flags[1], NEDGES + i);
        atomicAdd(&deg[dst], 1);
        return;
    }
    if (b < DEG_BLOCKS + CVT_BLOCKS) {
        int i = (b - DEG_BLOCKS) * 256 + threadIdx.x;
        if (i >= NNODES * FDIM / 4) return;
        if (flags[2]) {
            float4 v = ((const float4*)xin)[i];
            bf16x4 o;
            o[0] = f2b(v.x); o[1] = f2b(v.y); o[2] = f2b(v.z); o[3] = f2b(v.w);
            ((bf16x4*)xout)[i] = o;
        } else {
            ((uint2*)xout)[i] = ((const uint2*)xin)[i];
        }
        return;
    }
    int local_b = b - DEG_BLOCKS - CVT_BLOCKS;   // 0..61
    int fp32 = flags[3];
    if (local_b >= 59) {
        int t = (local_b - 59) * 256 + threadIdx.x;
        if (t >= 5 * 128) return;
        int which = t >> 7, idx = t & 127;
        const void* srcs[5] = {b1, b2, b3, b4, b5};
        int n = (which == 4) ? NCLS : 128;
        float v = 0.f;
        if (idx < n) v = ldf(srcs[which], fp32, idx);
        biasf[t] = v;
        return;
    }
    // weight pre-pack into MFMA B-fragment layout:
    // frag(kt,nt), lane: elem j = W[kbase + (lane>>4)*8 + j][nt*16 + (lane&15)]
    // layer1 0..63 | layer2 64..127 | layer3 128..191 | lin1 192..223 |
    // lin2 224..235 (KT=4, NT=3, cols >=40 zero-padded)
    int tid = local_b * 256 + threadIdx.x;
    int frag = tid >> 6, lane = tid & 63;
    if (frag >= 236) return;
    int q = lane >> 4, l16 = lane & 15;
    const void* W;
    int kbase, n, ldw = 128, nvalid = 128;
    if (frag < 192) {
        int g = frag >> 6, local = frag & 63;
        int kt = local >> 3, nt = local & 7;
        const void* Wl = (g == 0) ? Wl1 : (g == 1) ? Wl2 : Wl3;
        const void* Wr = (g == 0) ? Wr1 : (g == 1) ? Wr2 : Wr3;
        W = (kt < 4) ? Wl : Wr;
        kbase = (kt & 3) * 32;
        n = nt * 16 + l16;
    } else if (frag < 224) {
        int local = frag - 192;
        int kt = local >> 3, nt = local & 7;
        W = Wlin1;
        kbase = kt * 32;
        n = nt * 16 + l16;
    } else {
        int local = frag - 224;
        int kt = local / 3, nt = local % 3;
        W = Wlin2;
        kbase = kt * 32;
        n = nt * 16 + l16;
        ldw = NCLS;
        nvalid = NCLS;
    }
    bf16x8 v;
#pragma unroll
    for (int j = 0; j < 8; j++) {
        float e = 0.f;
        if (n < nvalid) e = ldf(W, fp32, (kbase + q * 8 + j) * ldw + n);
        v[j] = f2b(e);
    }
    packed[frag * 64 + lane] = v;
}

// ---------------------------------------------------------------------------
__global__ void k_alloc(const int* deg, int* counter, int* start, int* cursor) {
    __shared__ int s[256];
    __shared__ int sbase;
    int t = threadIdx.x;
    int i = blockIdx.x * 256 + t;
    int d = (i < NNODES) ? deg[i] : 0;
    s[t] = d;
    __syncthreads();
    for (int off = 1; off < 256; off <<= 1) {
        int v = (t >= off) ? s[t - off] : 0;
        __syncthreads();
        s[t] += v;
        __syncthreads();
    }
    if (t == 255) sbase = atomicAdd(counter, s[255]);
    __syncthreads();
    if (i < NNODES) {
        int st = sbase + s[t] - d;
        start[i] = st;
        cursor[i] = st;
    }
}

__global__ void k_fill(const int* e32, const long long* e64, const int* flags,
                       int* cursor, int* edge_src) {
    int i = blockIdx.x * 256 + threadIdx.x;
    if (i >= NEDGES) return;
    int is64 = flags[1];
    int src = edge_val(e32, e64, is64, i);
    int dst = edge_val(e32, e64, is64, NEDGES + i);
    int p = atomicAdd(&cursor[dst], 1);
    edge_src[p] = src;
}

// ---------------------------------------------------------------------------
// Mean aggregation: one wave per dst node; group g=lane>>4, c=lane&15 (16B).
// Edge indices preloaded coalesced (one per lane), distributed via shfl;
// 8 neighbors/iter with 2 independent 16B gathers; tail predicated.
__global__ void k_agg(const bf16* __restrict__ x, const int* __restrict__ start,
                      const int* __restrict__ deg, const int* __restrict__ edge_src,
                      bf16* __restrict__ aggb) {
    int w = threadIdx.x >> 6, lane = threadIdx.x & 63;
    int d = blockIdx.x * 4 + w;
    if (d >= NNODES) return;
    int s = start[d], dg = deg[d];
    int g = lane >> 4, c = lane & 15;
    int dcap = dg < 64 ? dg : 64;
    int eidx = (lane < dcap) ? edge_src[s + lane] : 0;
    float acc[8];
#pragma unroll
    for (int e = 0; e < 8; e++) acc[e] = 0.f;
    for (int i = 0; i < dcap; i += 8) {
        int j0 = i + g, j1 = i + 4 + g;
        int i0 = __shfl(eidx, j0 < dcap ? j0 : 0);
        int i1 = __shfl(eidx, j1 < dcap ? j1 : 0);
        if (j0 < dcap) {
            bf16x8 v0 = *(const bf16x8*)(x + (size_t)i0 * FDIM + c * 8);
#pragma unroll
            for (int e = 0; e < 8; e++) acc[e] += b2f(v0[e]);
        }
        if (j1 < dcap) {
            bf16x8 v1 = *(const bf16x8*)(x + (size_t)i1 * FDIM + c * 8);
#pragma unroll
            for (int e = 0; e < 8; e++) acc[e] += b2f(v1[e]);
        }
    }
    if (dg > 64) {
        for (int t = 64; t < dg; t++) {
            int src = edge_src[s + t];
            if (g == 0) {
                bf16x8 v0 = *(const bf16x8*)(x + (size_t)src * FDIM + c * 8);
#pragma unroll
                for (int e = 0; e < 8; e++) acc[e] += b2f(v0[e]);
            }
        }
    }
#pragma unroll
    for (int e = 0; e < 8; e++) {
        float a = acc[e];
        a += __shfl_xor(a, 16);
        a += __shfl_xor(a, 32);
        acc[e] = a;
    }
    if (g == 0) {
        float inv = (dg > 0) ? 1.f / (float)dg : 0.f;
        bf16x8 o;
#pragma unroll
        for (int e = 0; e < 8; e++) o[e] = f2b(acc[e] * inv);
        *(bf16x8*)(aggb + (size_t)d * FDIM + c * 8) = o;
    }
}

// ---------------------------------------------------------------------------
// SAGE GEMM (K=256: agg half + x half), M-split waves: wave = mt (16 rows),
// covers all 8 nt tiles. Per kt: 1 gathered A-load + 8 coalesced B-loads
// (identical across waves -> L1 hits) + 8 MFMA. Output relu(bf16), 128 cols.
__global__ void k_gemm(const bf16* __restrict__ xa, const bf16* __restrict__ xb,
                       const bf16x8* __restrict__ packed,
                       const float* __restrict__ bias, bf16* __restrict__ out) {
    const int lane = threadIdx.x & 63;
    const int wave = threadIdx.x >> 6;
    const int q = lane >> 4, l16 = lane & 15;
    const int rowbase = blockIdx.x * 64 + wave * 16;
    int rowA = rowbase + l16;
    if (rowA >= NNODES) rowA = NNODES - 1;

    f32x4 acc[8];
#pragma unroll
    for (int n = 0; n < 8; n++) acc[n] = (f32x4){0.f, 0.f, 0.f, 0.f};

#pragma unroll 2
    for (int kt = 0; kt < 8; kt++) {
        const bf16* src = (kt < 4) ? xa : xb;
        int klocal = (kt & 3) * 32;
        bf16x8 a = *(const bf16x8*)(src + (size_t)rowA * FDIM + klocal + q * 8);
        bf16x8 b[8];
#pragma unroll
        for (int n = 0; n < 8; n++)
            b[n] = packed[(kt * 8 + n) * 64 + lane];
#pragma unroll
        for (int n = 0; n < 8; n++)
            acc[n] = __builtin_amdgcn_mfma_f32_16x16x32_bf16(a, b[n], acc[n], 0, 0, 0);
    }

#pragma unroll
    for (int n = 0; n < 8; n++) {
        int col = n * 16 + l16;
        float bv = bias[col];
#pragma unroll
        for (int r = 0; r < 4; r++) {
            int row = rowbase + q * 4 + r;
            if (row < NNODES)
                out[(size_t)row * FDIM + col] = __float2bfloat16(fmaxf(acc[n][r] + bv, 0.f));
        }
    }
}

// ---------------------------------------------------------------------------
// Head: lin1 (K=128, relu) -> LDS -> lin2 (K=128, 40 cols) -> log_softmax
// -> fp32 out. Block = 64 rows, wave = 16-row slice.
#define H1STRIDE 136   // elems; 272B row stride -> 2-way-free LDS banks
__global__ void k_head(const bf16* __restrict__ h, const bf16x8* __restrict__ packed,
                       const float* __restrict__ bias1, const float* __restrict__ bias2,
                       float* __restrict__ out) {
    __shared__ short h1[64 * H1STRIDE];
    const int lane = threadIdx.x & 63;
    const int wave = threadIdx.x >> 6;
    const int q = lane >> 4, l16 = lane & 15;
    const int rowbase = blockIdx.x * 64 + wave * 16;
    int rowA = rowbase + l16;
    if (rowA >= NNODES) rowA = NNODES - 1;

    // ---- lin1 ----
    f32x4 acc[8];
#pragma unroll
    for (int n = 0; n < 8; n++) acc[n] = (f32x4){0.f, 0.f, 0.f, 0.f};
#pragma unroll 2
    for (int kt = 0; kt < 4; kt++) {
        bf16x8 a = *(const bf16x8*)(h + (size_t)rowA * FDIM + kt * 32 + q * 8);
        bf16x8 b[8];
#pragma unroll
        for (int n = 0; n < 8; n++)
            b[n] = packed[(192 + kt * 8 + n) * 64 + lane];
#pragma unroll
        for (int n = 0; n < 8; n++)
            acc[n] = __builtin_amdgcn_mfma_f32_16x16x32_bf16(a, b[n], acc[n], 0, 0, 0);
    }
#pragma unroll
    for (int n = 0; n < 8; n++) {
        int col = n * 16 + l16;
        float bv = bias1[col];
#pragma unroll
        for (int r = 0; r < 4; r++) {
            int rl = wave * 16 + q * 4 + r;
            h1[rl * H1STRIDE + col] = f2b(fmaxf(acc[n][r] + bv, 0.f));
        }
    }
    __syncthreads();

    // ---- lin2 (K=128 from LDS) ----
    f32x4 acc2[3];
#pragma unroll
    for (int n = 0; n < 3; n++) acc2[n] = (f32x4){0.f, 0.f, 0.f, 0.f};
#pragma unroll
    for (int kt = 0; kt < 4; kt++) {
        bf16x8 a = *(const bf16x8*)(h1 + (wave * 16 + l16) * H1STRIDE + kt * 32 + q * 8);
        bf16x8 b[3];
#pragma unroll
        for (int n = 0; n < 3; n++)
            b[n] = packed[(224 + kt * 3 + n) * 64 + lane];
#pragma unroll
        for (int n = 0; n < 3; n++)
            acc2[n] = __builtin_amdgcn_mfma_f32_16x16x32_bf16(a, b[n], acc2[n], 0, 0, 0);
    }

    // ---- log_softmax over 40 cols, per row (cols live in 16-lane group) ----
    const float NEG = -1e30f;
    bool v2ok = (l16 < 8);
#pragma unroll
    for (int r = 0; r < 4; r++) {
        int row = rowbase + q * 4 + r;
        float v0 = acc2[0][r] + bias2[l16];
        float v1 = acc2[1][r] + bias2[16 + l16];
        float v2 = v2ok ? (acc2[2][r] + bias2[32 + l16]) : NEG;
        float m = fmaxf(fmaxf(v0, v1), v2);
#pragma unroll
        for (int mask = 1; mask < 16; mask <<= 1)
            m = fmaxf(m, __shfl_xor(m, mask));
        float s = expf(v0 - m) + expf(v1 - m) + (v2ok ? expf(v2 - m) : 0.f);
#pragma unroll
        for (int mask = 1; mask < 16; mask <<= 1)
            s += __shfl_xor(s, mask);
        float l = m + logf(s);
        if (row < NNODES) {
            out[(size_t)row * NCLS + l16] = v0 - l;
            out[(size_t)row * NCLS + 16 + l16] = v1 - l;
            if (v2ok) out[(size_t)row * NCLS + 32 + l16] = v2 - l;
        }
    }
}

// ---------------------------------------------------------------------------
extern "C" void kernel_launch(void* const* d_in, const int* in_sizes, int n_in,
                              void* d_out, int out_size, void* d_ws, size_t ws_size,
                              hipStream_t stream) {
    const int* e32 = (const int*)d_in[1];
    const long long* e64 = (const long long*)d_in[1];

    char* ws = (char*)d_ws;
    size_t off = 0;
    auto take = [&](size_t bytes) {
        void* p = ws + off;
        off = (off + bytes + 255) & ~(size_t)255;
        return p;
    };
    int* deg      = (int*)take(NNODES * 4);
    int* start    = (int*)take(NNODES * 4);
    int* cursor   = (int*)take(NNODES * 4);
    int* flags    = (int*)take(256);
    int* edge_src = (int*)take(NEDGES * 4);
    bf16x8* packed = (bf16x8*)take(236 * 64 * 16);
    float* biasf  = (float*)take(5 * 128 * 4);
    bf16* xb      = (bf16*)take((size_t)NNODES * FDIM * 2);
    bf16* aggb    = (bf16*)take((size_t)NNODES * FDIM * 2);
    bf16* bufA    = (bf16*)take((size_t)NNODES * FDIM * 2);
    bf16* bufB    = xb;        // x dead after layer-1 gemm

    k_init<<<200, 256, 0, stream>>>((const unsigned int*)d_in[1],
                                    (const unsigned int*)d_in[0],
                                    (const unsigned int*)d_in[2], flags, deg);

    k_stage1<<<DEG_BLOCKS + CVT_BLOCKS + 62, 256, 0, stream>>>(
        e32, e64, d_in[0],
        d_in[2], d_in[4], d_in[5], d_in[7], d_in[8], d_in[10], d_in[11], d_in[13],
        d_in[3], d_in[6], d_in[9], d_in[12], d_in[14],
        flags, deg, xb, packed, biasf);

    k_alloc<<<(NNODES + 255) / 256, 256, 0, stream>>>(deg, flags, start, cursor);
    k_fill<<<(NEDGES + 255) / 256, 256, 0, stream>>>(e32, e64, flags, cursor, edge_src);

    const int AB = (NNODES + 3) / 4;
    const int GB = (NNODES + 63) / 64;

    // layer 1: xb -> bufA
    k_agg<<<AB, 256, 0, stream>>>(xb, start, deg, edge_src, aggb);
    k_gemm<<<GB, 256, 0, stream>>>(aggb, xb, packed + 0 * 64, biasf + 0, bufA);
    // layer 2: bufA -> bufB (aliases xb)
    k_agg<<<AB, 256, 0, stream>>>(bufA, start, deg, edge_src, aggb);
    k_gemm<<<GB, 256, 0, stream>>>(aggb, bufA, packed + 64 * 64, biasf + 128, bufB);
    // layer 3: bufB -> bufA
    k_agg<<<AB, 256, 0, stream>>>(bufB, start, deg, edge_src, aggb);
    k_gemm<<<GB, 256, 0, stream>>>(aggb, bufB, packed + 128 * 64, biasf + 256, bufA);
    // head: lin1 + lin2 + log_softmax -> fp32 out
    k_head<<<GB, 256, 0, stream>>>(bufA, packed, biasf + 384, biasf + 512,
                                   (float*)d_out);
}